// Round 10
// baseline (638.345 us; speedup 1.0000x reference)
//
#include <hip/hip_runtime.h>
#include <hip/hip_bf16.h>

// LightGCN on MI355X — round 10.
// R7 spmm8 structure (8-lane groups own a row; lane owns an 8-dim slice) +
//  - degree-sorted row permutation (counting sort, exact-degree bins) so all
//    8 rows in a wave have EQUAL degree -> no intra-wave divergence
//  - phantom zero row at z[N_NODES] -> branch-free uniform trip count
//  - 16 gathers (16 KB) in flight per wave-iteration
// Layers 0/1 write only bf16 z; last layer writes
// out = init + z1/dinv + (z2/dinv)/2 + xn3/3 (NT streams).

constexpr int N_USERS = 100000;
constexpr int N_ITEMS = 50000;
constexpr int N_NODES = N_USERS + N_ITEMS;
constexpr int D = 64;
constexpr int NBK  = 196;
constexpr int SLOT = 12288;
constexpr int EPB  = 16384;
constexpr int BPAD = 16;          // degree-bin padding (64 B) to avoid line contention

typedef unsigned int uint4v  __attribute__((ext_vector_type(4)));
typedef float        float4v __attribute__((ext_vector_type(4)));

__device__ inline unsigned f2bf(float f) {
    unsigned u = __float_as_uint(f);
    u += 0x7FFFu + ((u >> 16) & 1u);   // RNE
    return u >> 16;
}
__device__ inline float bflo(unsigned u) { return __uint_as_float(u << 16); }
__device__ inline float bfhi(unsigned u) { return __uint_as_float(u & 0xFFFF0000u); }

__device__ inline int lower_bound(const int* __restrict__ a, int n, int key) {
    int lo = 0, hi = n;
    while (lo < hi) { int m = (lo + hi) >> 1; if (a[m] < key) lo = m + 1; else hi = m; }
    return lo;
}

// ---- user row_ptr + user dinv + bcur init + user degree hist ----
__global__ __launch_bounds__(256) void rpu_kernel(
    const int* __restrict__ rows, int* __restrict__ rpu,
    float* __restrict__ dinv, int* __restrict__ bcur,
    int* __restrict__ ghist, int Eh)
{
    if (blockIdx.x == 0 && threadIdx.x < NBK) bcur[threadIdx.x] = threadIdx.x * SLOT;
    int i = blockIdx.x * 256 + threadIdx.x;
    if (i > N_USERS) return;
    int lo = lower_bound(rows, Eh, i);
    rpu[i] = lo;
    int lane = threadIdx.x & 63;
    int nxt = __shfl_down(lo, 1);
    if (lane == 63 || i >= N_USERS)
        nxt = (i < N_USERS) ? lower_bound(rows, Eh, i + 1) : lo;
    if (i < N_USERS) {
        int deg = nxt - lo;
        dinv[i] = rsqrtf((float)deg + 1e-7f);
        atomicAdd(&ghist[min(deg, 255) * BPAD], 1);
    }
}

// ---- pass 1: bucket scatter of (u, vlocal) from the first edge half ----
__global__ __launch_bounds__(256) void bucket_scatter(
    const int* __restrict__ rows, const int* __restrict__ cols,
    int* __restrict__ bcur, int* __restrict__ staging, int Eh)
{
    __shared__ int hist[256];
    const int tid = threadIdx.x;
    const int base = blockIdx.x * EPB;
    const int nEdge = min(EPB, Eh - base);
    if (nEdge <= 0) return;

    hist[tid] = 0;
    __syncthreads();

    for (int s = 0; s < 16; ++s) {
        int o = s * 1024 + tid * 4;
        if (o + 3 < nEdge) {
            int4 c4 = *reinterpret_cast<const int4*>(cols + base + o);
            atomicAdd(&hist[(c4.x - N_USERS) >> 8], 1);
            atomicAdd(&hist[(c4.y - N_USERS) >> 8], 1);
            atomicAdd(&hist[(c4.z - N_USERS) >> 8], 1);
            atomicAdd(&hist[(c4.w - N_USERS) >> 8], 1);
        } else if (o < nEdge) {
            for (int k = o; k < nEdge; ++k)
                atomicAdd(&hist[(cols[base + k] - N_USERS) >> 8], 1);
        }
    }
    __syncthreads();

    if (tid < NBK) {
        int h = hist[tid];
        hist[tid] = (h > 0) ? atomicAdd(&bcur[tid], h) : 0;
    }
    __syncthreads();

    for (int s = 0; s < 16; ++s) {
        int o = s * 1024 + tid * 4;
        if (o + 3 < nEdge) {
            int4 c4 = *reinterpret_cast<const int4*>(cols + base + o);
            int4 u4 = *reinterpret_cast<const int4*>(rows + base + o);
            int v, p;
            v = c4.x - N_USERS; p = atomicAdd(&hist[v >> 8], 1);
            staging[p] = ((v & 255) << 24) | u4.x;
            v = c4.y - N_USERS; p = atomicAdd(&hist[v >> 8], 1);
            staging[p] = ((v & 255) << 24) | u4.y;
            v = c4.z - N_USERS; p = atomicAdd(&hist[v >> 8], 1);
            staging[p] = ((v & 255) << 24) | u4.z;
            v = c4.w - N_USERS; p = atomicAdd(&hist[v >> 8], 1);
            staging[p] = ((v & 255) << 24) | u4.w;
        } else if (o < nEdge) {
            for (int k = o; k < nEdge; ++k) {
                int v = cols[base + k] - N_USERS;
                int u = rows[base + k];
                int p = atomicAdd(&hist[v >> 8], 1);
                staging[p] = ((v & 255) << 24) | u;
            }
        }
    }
}

// ---- pass 2: per-bucket sort -> item CSR + rpi + item dinv + item deg hist ----
__global__ __launch_bounds__(256) void item_csr(
    const int* __restrict__ bcur, const int* __restrict__ staging,
    int* __restrict__ rpi, float* __restrict__ dinv, int* __restrict__ csr,
    int* __restrict__ ghist)
{
    __shared__ int hist[256];
    __shared__ int cur[256];
    __shared__ int wsum[4];
    __shared__ int s_cbase;
    const int b = blockIdx.x;
    const int tid = threadIdx.x, lane = tid & 63, w = tid >> 6;

    int tot = (tid < NBK) ? (bcur[tid] - tid * SLOT) : 0;
    int incl = tot;
    #pragma unroll
    for (int off = 1; off < 64; off <<= 1) {
        int s = __shfl_up(incl, off);
        if (lane >= off) incl += s;
    }
    if (lane == 63) wsum[w] = incl;
    __syncthreads();
    int woff = 0;
    #pragma unroll
    for (int k = 0; k < 4; ++k) woff += (k < w) ? wsum[k] : 0;
    int excl = woff + incl - tot;
    if (tid == b) s_cbase = excl;
    if (b == 0 && tid == NBK - 1) rpi[N_ITEMS] = excl + tot;
    __syncthreads();

    const int sbase = b * SLOT;
    const int n = bcur[b] - sbase;
    const int cbase = s_cbase;

    hist[tid] = 0;
    __syncthreads();
    for (int i = tid; i < n; i += 256)
        atomicAdd(&hist[((unsigned)staging[sbase + i]) >> 24], 1);
    __syncthreads();

    int h = hist[tid];
    int incl2 = h;
    #pragma unroll
    for (int off = 1; off < 64; off <<= 1) {
        int s = __shfl_up(incl2, off);
        if (lane >= off) incl2 += s;
    }
    if (lane == 63) wsum[w] = incl2;
    __syncthreads();
    int woff2 = 0;
    #pragma unroll
    for (int k = 0; k < 4; ++k) woff2 += (k < w) ? wsum[k] : 0;
    int excl2 = woff2 + incl2 - h;

    int gitem = b * 256 + tid;
    if (gitem < N_ITEMS) {
        rpi[gitem] = cbase + excl2;
        dinv[N_USERS + gitem] = rsqrtf((float)h + 1e-7f);
        atomicAdd(&ghist[min(h, 255) * BPAD], 1);
    }
    cur[tid] = cbase + excl2;
    __syncthreads();

    for (int i = tid; i < n; i += 256) {
        int e = staging[sbase + i];
        int p = atomicAdd(&cur[((unsigned)e) >> 24], 1);
        csr[p] = e & 0xFFFFFF;
    }
}

// ---- degree-bin exclusive scan (256 bins, 1 block) ----
__global__ __launch_bounds__(256) void deg_scan(
    const int* __restrict__ ghist, int* __restrict__ gcur)
{
    __shared__ int wsum[4];
    const int tid = threadIdx.x, lane = tid & 63, w = tid >> 6;
    int v = ghist[tid * BPAD];
    int incl = v;
    #pragma unroll
    for (int off = 1; off < 64; off <<= 1) {
        int s = __shfl_up(incl, off);
        if (lane >= off) incl += s;
    }
    if (lane == 63) wsum[w] = incl;
    __syncthreads();
    int woff = 0;
    #pragma unroll
    for (int k = 0; k < 4; ++k) woff += (k < w) ? wsum[k] : 0;
    gcur[tid * BPAD] = woff + incl - v;
}

// ---- scatter rows into degree-sorted permutation ----
__global__ __launch_bounds__(256) void deg_scatter(
    const int* __restrict__ rpu, const int* __restrict__ rpi,
    int* __restrict__ gcur, int* __restrict__ perm)
{
    int i = blockIdx.x * 256 + threadIdx.x;
    if (i >= N_NODES) return;
    int deg = (i < N_USERS) ? rpu[i + 1] - rpu[i]
                            : rpi[i - N_USERS + 1] - rpi[i - N_USERS];
    int pos = atomicAdd(&gcur[min(deg, 255) * BPAD], 1);
    perm[pos] = i;
}

// ---- prep: z0[r] = dinv[r]*in_embs[r] in bf16; zero phantom row in zP & zQ ----
__global__ __launch_bounds__(256) void prep0(
    const float* __restrict__ init, const float* __restrict__ dinv,
    unsigned short* __restrict__ zP, unsigned short* __restrict__ zQ)
{
    int i = blockIdx.x * 256 + threadIdx.x;      // uint2 (4 bf16) units
    const int TOT = N_NODES * 16;
    if (i < TOT) {
        int r = i >> 4;
        float dv = dinv[r];
        float4 x = reinterpret_cast<const float4*>(init)[i];
        unsigned lo0 = f2bf(x.x * dv), hi0 = f2bf(x.y * dv);
        unsigned lo1 = f2bf(x.z * dv), hi1 = f2bf(x.w * dv);
        uint2 o; o.x = lo0 | (hi0 << 16); o.y = lo1 | (hi1 << 16);
        reinterpret_cast<uint2*>(zP)[i] = o;
    } else if (i < TOT + 16) {
        uint2 zz; zz.x = 0; zz.y = 0;
        reinterpret_cast<uint2*>(zP)[i] = zz;
        reinterpret_cast<uint2*>(zQ)[i] = zz;
    }
}

// ---- fused SpMM + L2-normalize (+ z write | final combine) ----
// 8-lane group per row (degree-sorted), lane owns an 8-dim (16 B) slice.
#define ACC8(r) do { \
    a0 += bflo(r.x); a1 += bfhi(r.x); \
    a2 += bflo(r.y); a3 += bfhi(r.y); \
    a4 += bflo(r.z); a5 += bfhi(r.z); \
    a6 += bflo(r.w); a7 += bfhi(r.w); } while (0)

template<int LAST>
__global__ __launch_bounds__(256) void spmm8(
    const unsigned short* __restrict__ z,
    const int* __restrict__ perm,
    const int* __restrict__ rpu,
    const int* __restrict__ rpi,
    const int* __restrict__ cols_u,
    const int* __restrict__ csr_col_i,
    const float* __restrict__ dinv,
    unsigned short* __restrict__ zout,
    const unsigned short* z1,
    const unsigned short* z2,
    const float* __restrict__ init,
    float* __restrict__ out)
{
    const int tid = threadIdx.x;
    const int lane = tid & 63;
    const int g  = lane >> 3;
    const int sl = lane & 7;
    const int wave = tid >> 6;
    const int slot = blockIdx.x * 32 + wave * 8 + g;
    if (slot >= N_NODES) return;
    const int row = perm[slot];
    const int gb = g << 3;
    const int ZR = N_NODES;                     // phantom zero row

    int beg, end;
    const int* clist;
    if (row < N_USERS) {
        beg = rpu[row]; end = rpu[row + 1]; clist = cols_u;
    } else {
        int v = row - N_USERS;
        beg = rpi[v]; end = rpi[v + 1]; clist = csr_col_i;
    }

    float a0=0.f,a1=0.f,a2=0.f,a3=0.f,a4=0.f,a5=0.f,a6=0.f,a7=0.f;
    const unsigned short* zs = z + (size_t)sl * 8;

    const int nit = (end - beg + 15) >> 4;      // uniform within wave (deg-sorted)
    int j = beg;
    for (int t = 0; t < nit; ++t, j += 16) {
        int iA = j + sl, iB = j + 8 + sl;
        int cA = (iA < end) ? __builtin_nontemporal_load(clist + iA) : ZR;
        int cB = (iB < end) ? __builtin_nontemporal_load(clist + iB) : ZR;
        int A0=__shfl(cA,gb+0), A1=__shfl(cA,gb+1), A2=__shfl(cA,gb+2), A3=__shfl(cA,gb+3);
        int A4=__shfl(cA,gb+4), A5=__shfl(cA,gb+5), A6=__shfl(cA,gb+6), A7=__shfl(cA,gb+7);
        uint4 rA0 = *reinterpret_cast<const uint4*>(zs + (size_t)A0 * D);
        uint4 rA1 = *reinterpret_cast<const uint4*>(zs + (size_t)A1 * D);
        uint4 rA2 = *reinterpret_cast<const uint4*>(zs + (size_t)A2 * D);
        uint4 rA3 = *reinterpret_cast<const uint4*>(zs + (size_t)A3 * D);
        uint4 rA4 = *reinterpret_cast<const uint4*>(zs + (size_t)A4 * D);
        uint4 rA5 = *reinterpret_cast<const uint4*>(zs + (size_t)A5 * D);
        uint4 rA6 = *reinterpret_cast<const uint4*>(zs + (size_t)A6 * D);
        uint4 rA7 = *reinterpret_cast<const uint4*>(zs + (size_t)A7 * D);
        int B0=__shfl(cB,gb+0), B1=__shfl(cB,gb+1), B2=__shfl(cB,gb+2), B3=__shfl(cB,gb+3);
        int B4=__shfl(cB,gb+4), B5=__shfl(cB,gb+5), B6=__shfl(cB,gb+6), B7=__shfl(cB,gb+7);
        uint4 rB0 = *reinterpret_cast<const uint4*>(zs + (size_t)B0 * D);
        uint4 rB1 = *reinterpret_cast<const uint4*>(zs + (size_t)B1 * D);
        uint4 rB2 = *reinterpret_cast<const uint4*>(zs + (size_t)B2 * D);
        uint4 rB3 = *reinterpret_cast<const uint4*>(zs + (size_t)B3 * D);
        uint4 rB4 = *reinterpret_cast<const uint4*>(zs + (size_t)B4 * D);
        uint4 rB5 = *reinterpret_cast<const uint4*>(zs + (size_t)B5 * D);
        uint4 rB6 = *reinterpret_cast<const uint4*>(zs + (size_t)B6 * D);
        uint4 rB7 = *reinterpret_cast<const uint4*>(zs + (size_t)B7 * D);
        ACC8(rA0); ACC8(rA1); ACC8(rA2); ACC8(rA3);
        ACC8(rA4); ACC8(rA5); ACC8(rA6); ACC8(rA7);
        ACC8(rB0); ACC8(rB1); ACC8(rB2); ACC8(rB3);
        ACC8(rB4); ACC8(rB5); ACC8(rB6); ACC8(rB7);
    }

    float ss = a0*a0 + a1*a1 + a2*a2 + a3*a3 + a4*a4 + a5*a5 + a6*a6 + a7*a7;
    ss += __shfl_xor(ss, 1);
    ss += __shfl_xor(ss, 2);
    ss += __shfl_xor(ss, 4);
    float rinv = 1.0f / fmaxf(sqrtf(ss), 1e-12f);

    size_t idx = (size_t)row * D + (size_t)sl * 8;
    if (!LAST) {
        float sc = rinv * dinv[row];
        uint4 zo;
        zo.x = f2bf(a0 * sc) | (f2bf(a1 * sc) << 16);
        zo.y = f2bf(a2 * sc) | (f2bf(a3 * sc) << 16);
        zo.z = f2bf(a4 * sc) | (f2bf(a5 * sc) << 16);
        zo.w = f2bf(a6 * sc) | (f2bf(a7 * sc) << 16);
        *reinterpret_cast<uint4*>(zout + idx) = zo;
    } else {
        float recip = 1.0f / dinv[row];          // = sqrt(deg + eps)
        float k1 = recip, k2 = 0.5f * recip, k3 = rinv * (1.0f / 3.0f);
        uint4v w1 = __builtin_nontemporal_load(reinterpret_cast<const uint4v*>(z1 + idx));
        uint4v w2 = __builtin_nontemporal_load(reinterpret_cast<const uint4v*>(z2 + idx));
        const float4v* ip = reinterpret_cast<const float4v*>(init + idx);
        float4v o0 = __builtin_nontemporal_load(ip);
        float4v o1 = __builtin_nontemporal_load(ip + 1);
        o0.x += bflo(w1.x) * k1 + bflo(w2.x) * k2 + a0 * k3;
        o0.y += bfhi(w1.x) * k1 + bfhi(w2.x) * k2 + a1 * k3;
        o0.z += bflo(w1.y) * k1 + bflo(w2.y) * k2 + a2 * k3;
        o0.w += bfhi(w1.y) * k1 + bfhi(w2.y) * k2 + a3 * k3;
        o1.x += bflo(w1.z) * k1 + bflo(w2.z) * k2 + a4 * k3;
        o1.y += bfhi(w1.z) * k1 + bfhi(w2.z) * k2 + a5 * k3;
        o1.z += bflo(w1.w) * k1 + bflo(w2.w) * k2 + a6 * k3;
        o1.w += bfhi(w1.w) * k1 + bfhi(w2.w) * k2 + a7 * k3;
        float4v* op = reinterpret_cast<float4v*>(out + idx);
        __builtin_nontemporal_store(o0, op);
        __builtin_nontemporal_store(o1, op + 1);
    }
}

extern "C" void kernel_launch(void* const* d_in, const int* in_sizes, int n_in,
                              void* d_out, int out_size, void* d_ws, size_t ws_size,
                              hipStream_t stream) {
    const float* in_embs = (const float*)d_in[0];
    const int*   rows    = (const int*)d_in[1];
    const int*   cols    = (const int*)d_in[2];
    float* out = (float*)d_out;

    const int E  = in_sizes[1];
    const int Eh = E / 2;
    const size_t z_bytes = (size_t)(N_NODES + 1) * D * sizeof(unsigned short); // +zero row

    auto align256 = [](size_t x) { return (x + 255) & ~(size_t)255; };
    char* p = (char*)d_ws;
    unsigned short* zP = (unsigned short*)p; p += align256(z_bytes);
    unsigned short* zQ = (unsigned short*)p; p += align256(z_bytes);
    int*   csr_col_i = (int*)p;   p += align256((size_t)Eh * sizeof(int));
    int*   rpu       = (int*)p;   p += align256((size_t)(N_USERS + 1) * sizeof(int));
    int*   rpi       = (int*)p;   p += align256((size_t)(N_ITEMS + 1) * sizeof(int));
    float* dinv      = (float*)p; p += align256((size_t)N_NODES * sizeof(float));
    int*   bcur      = (int*)p;   p += align256(256 * sizeof(int));
    int*   ghist     = (int*)p;   p += align256(256 * BPAD * sizeof(int));
    int*   gcur      = (int*)p;   p += align256(256 * BPAD * sizeof(int));
    int*   perm      = (int*)p;   p += align256((size_t)N_NODES * sizeof(int));
    // staging aliases zP (9.63 MB < 19.2 MB); consumed by item_csr before prep0
    int*   staging   = (int*)zP;

    // --- CSR build + degree sort ---
    hipMemsetAsync(ghist, 0, 256 * BPAD * sizeof(int), stream);
    rpu_kernel<<<(N_USERS + 256) / 256, 256, 0, stream>>>(rows, rpu, dinv, bcur, ghist, Eh);
    bucket_scatter<<<(Eh + EPB - 1) / EPB, 256, 0, stream>>>(rows, cols, bcur, staging, Eh);
    item_csr<<<NBK, 256, 0, stream>>>(bcur, staging, rpi, dinv, csr_col_i, ghist);
    deg_scan<<<1, 256, 0, stream>>>(ghist, gcur);
    deg_scatter<<<(N_NODES + 255) / 256, 256, 0, stream>>>(rpu, rpi, gcur, perm);
    prep0<<<(N_NODES * 16 + 16 + 255) / 256, 256, 0, stream>>>(in_embs, dinv, zP, zQ);

    // --- 3 propagation layers ---
    const int grid = (N_NODES + 31) / 32;
    spmm8<0><<<grid, 256, 0, stream>>>(zP, perm, rpu, rpi, cols, csr_col_i, dinv,
                                       zQ, nullptr, nullptr, nullptr, nullptr);
    spmm8<0><<<grid, 256, 0, stream>>>(zQ, perm, rpu, rpi, cols, csr_col_i, dinv,
                                       zP, nullptr, nullptr, nullptr, nullptr);
    spmm8<1><<<grid, 256, 0, stream>>>(zP, perm, rpu, rpi, cols, csr_col_i, dinv,
                                       nullptr, zQ, zP, in_embs, out);
}

// Round 11
// 260.872 us; speedup vs baseline: 2.4470x; 2.4470x over previous
//
#include <hip/hip_runtime.h>
#include <hip/hip_bf16.h>

// LightGCN on MI355X — round 11.
// Degree-sorted spmm8 (R10 idea) with the build de-poisoned:
//  - rpu via boundary detection on sorted rows (no binary search)
//  - degree histograms via LDS + per-(block,bin) merge (no contended atomics)
//  - deg_scatter via LDS local-rank + per-(block,bin) reservation
//  - spmm8: 16-gather loop + 8-step + phantom-padded remainder (<=7 waste)

constexpr int N_USERS = 100000;
constexpr int N_ITEMS = 50000;
constexpr int N_NODES = N_USERS + N_ITEMS;
constexpr int D = 64;
constexpr int NBK  = 196;
constexpr int SLOT = 12288;
constexpr int EPB  = 16384;
constexpr int BPAD = 16;          // degree-bin padding (64 B lines)

typedef unsigned int uint4v  __attribute__((ext_vector_type(4)));
typedef float        float4v __attribute__((ext_vector_type(4)));

__device__ inline unsigned f2bf(float f) {
    unsigned u = __float_as_uint(f);
    u += 0x7FFFu + ((u >> 16) & 1u);   // RNE
    return u >> 16;
}
__device__ inline float bflo(unsigned u) { return __uint_as_float(u << 16); }
__device__ inline float bfhi(unsigned u) { return __uint_as_float(u & 0xFFFF0000u); }

// ---- rpu via boundary fill over sorted rows[0:Eh]; also init bcur ----
__global__ __launch_bounds__(256) void edge_bounds(
    const int* __restrict__ rows, int* __restrict__ rpu,
    int* __restrict__ bcur, int Eh)
{
    if (blockIdx.x == 0 && threadIdx.x < NBK) bcur[threadIdx.x] = threadIdx.x * SLOT;
    int j = blockIdx.x * 256 + threadIdx.x;
    if (j >= Eh) return;
    int r = rows[j];
    int rprev = (j == 0) ? -1 : rows[j - 1];
    for (int k = rprev + 1; k <= r; ++k) rpu[k] = j;
    if (j == Eh - 1)
        for (int k = r + 1; k <= N_USERS; ++k) rpu[k] = Eh;
}

// ---- user dinv + degree histogram (LDS, then per-(block,bin) merge) ----
__global__ __launch_bounds__(256) void user_dinv(
    const int* __restrict__ rpu, float* __restrict__ dinv, int* __restrict__ ghist)
{
    __shared__ int h[256];
    const int tid = threadIdx.x;
    h[tid] = 0;
    __syncthreads();
    int i = blockIdx.x * 256 + tid;
    if (i < N_USERS) {
        int deg = rpu[i + 1] - rpu[i];
        dinv[i] = rsqrtf((float)deg + 1e-7f);
        atomicAdd(&h[min(deg, 255)], 1);
    }
    __syncthreads();
    if (h[tid]) atomicAdd(&ghist[tid * BPAD], h[tid]);
}

// ---- pass 1: bucket scatter of (u, vlocal) from the first edge half ----
__global__ __launch_bounds__(256) void bucket_scatter(
    const int* __restrict__ rows, const int* __restrict__ cols,
    int* __restrict__ bcur, int* __restrict__ staging, int Eh)
{
    __shared__ int hist[256];
    const int tid = threadIdx.x;
    const int base = blockIdx.x * EPB;
    const int nEdge = min(EPB, Eh - base);
    if (nEdge <= 0) return;

    hist[tid] = 0;
    __syncthreads();

    for (int s = 0; s < 16; ++s) {
        int o = s * 1024 + tid * 4;
        if (o + 3 < nEdge) {
            int4 c4 = *reinterpret_cast<const int4*>(cols + base + o);
            atomicAdd(&hist[(c4.x - N_USERS) >> 8], 1);
            atomicAdd(&hist[(c4.y - N_USERS) >> 8], 1);
            atomicAdd(&hist[(c4.z - N_USERS) >> 8], 1);
            atomicAdd(&hist[(c4.w - N_USERS) >> 8], 1);
        } else if (o < nEdge) {
            for (int k = o; k < nEdge; ++k)
                atomicAdd(&hist[(cols[base + k] - N_USERS) >> 8], 1);
        }
    }
    __syncthreads();

    if (tid < NBK) {
        int h = hist[tid];
        hist[tid] = (h > 0) ? atomicAdd(&bcur[tid], h) : 0;
    }
    __syncthreads();

    for (int s = 0; s < 16; ++s) {
        int o = s * 1024 + tid * 4;
        if (o + 3 < nEdge) {
            int4 c4 = *reinterpret_cast<const int4*>(cols + base + o);
            int4 u4 = *reinterpret_cast<const int4*>(rows + base + o);
            int v, p;
            v = c4.x - N_USERS; p = atomicAdd(&hist[v >> 8], 1);
            staging[p] = ((v & 255) << 24) | u4.x;
            v = c4.y - N_USERS; p = atomicAdd(&hist[v >> 8], 1);
            staging[p] = ((v & 255) << 24) | u4.y;
            v = c4.z - N_USERS; p = atomicAdd(&hist[v >> 8], 1);
            staging[p] = ((v & 255) << 24) | u4.z;
            v = c4.w - N_USERS; p = atomicAdd(&hist[v >> 8], 1);
            staging[p] = ((v & 255) << 24) | u4.w;
        } else if (o < nEdge) {
            for (int k = o; k < nEdge; ++k) {
                int v = cols[base + k] - N_USERS;
                int u = rows[base + k];
                int p = atomicAdd(&hist[v >> 8], 1);
                staging[p] = ((v & 255) << 24) | u;
            }
        }
    }
}

// ---- pass 2: per-bucket sort -> item CSR + rpi + item dinv + deg hist ----
__global__ __launch_bounds__(256) void item_csr(
    const int* __restrict__ bcur, const int* __restrict__ staging,
    int* __restrict__ rpi, float* __restrict__ dinv, int* __restrict__ csr,
    int* __restrict__ ghist)
{
    __shared__ int hist[256];
    __shared__ int cur[256];
    __shared__ int dh[256];
    __shared__ int wsum[4];
    __shared__ int s_cbase;
    const int b = blockIdx.x;
    const int tid = threadIdx.x, lane = tid & 63, w = tid >> 6;

    int tot = (tid < NBK) ? (bcur[tid] - tid * SLOT) : 0;
    int incl = tot;
    #pragma unroll
    for (int off = 1; off < 64; off <<= 1) {
        int s = __shfl_up(incl, off);
        if (lane >= off) incl += s;
    }
    if (lane == 63) wsum[w] = incl;
    __syncthreads();
    int woff = 0;
    #pragma unroll
    for (int k = 0; k < 4; ++k) woff += (k < w) ? wsum[k] : 0;
    int excl = woff + incl - tot;
    if (tid == b) s_cbase = excl;
    if (b == 0 && tid == NBK - 1) rpi[N_ITEMS] = excl + tot;
    __syncthreads();

    const int sbase = b * SLOT;
    const int n = bcur[b] - sbase;
    const int cbase = s_cbase;

    hist[tid] = 0;
    dh[tid] = 0;
    __syncthreads();
    for (int i = tid; i < n; i += 256)
        atomicAdd(&hist[((unsigned)staging[sbase + i]) >> 24], 1);
    __syncthreads();

    int h = hist[tid];
    int incl2 = h;
    #pragma unroll
    for (int off = 1; off < 64; off <<= 1) {
        int s = __shfl_up(incl2, off);
        if (lane >= off) incl2 += s;
    }
    if (lane == 63) wsum[w] = incl2;
    __syncthreads();
    int woff2 = 0;
    #pragma unroll
    for (int k = 0; k < 4; ++k) woff2 += (k < w) ? wsum[k] : 0;
    int excl2 = woff2 + incl2 - h;

    int gitem = b * 256 + tid;
    if (gitem < N_ITEMS) {
        rpi[gitem] = cbase + excl2;
        dinv[N_USERS + gitem] = rsqrtf((float)h + 1e-7f);
        atomicAdd(&dh[min(h, 255)], 1);
    }
    cur[tid] = cbase + excl2;
    __syncthreads();

    if (dh[tid]) atomicAdd(&ghist[tid * BPAD], dh[tid]);

    for (int i = tid; i < n; i += 256) {
        int e = staging[sbase + i];
        int p = atomicAdd(&cur[((unsigned)e) >> 24], 1);
        csr[p] = e & 0xFFFFFF;
    }
}

// ---- degree-bin exclusive scan (256 bins, 1 block) ----
__global__ __launch_bounds__(256) void deg_scan(
    const int* __restrict__ ghist, int* __restrict__ gcur)
{
    __shared__ int wsum[4];
    const int tid = threadIdx.x, lane = tid & 63, w = tid >> 6;
    int v = ghist[tid * BPAD];
    int incl = v;
    #pragma unroll
    for (int off = 1; off < 64; off <<= 1) {
        int s = __shfl_up(incl, off);
        if (lane >= off) incl += s;
    }
    if (lane == 63) wsum[w] = incl;
    __syncthreads();
    int woff = 0;
    #pragma unroll
    for (int k = 0; k < 4; ++k) woff += (k < w) ? wsum[k] : 0;
    gcur[tid * BPAD] = woff + incl - v;
}

// ---- degree-sorted permutation: LDS local rank + per-(block,bin) reserve ----
__global__ __launch_bounds__(256) void deg_scatter(
    const int* __restrict__ rpu, const int* __restrict__ rpi,
    int* __restrict__ gcur, int* __restrict__ perm)
{
    __shared__ int lh[256];
    __shared__ int lbase[256];
    const int tid = threadIdx.x;
    const int i = blockIdx.x * 256 + tid;
    lh[tid] = 0;
    __syncthreads();
    int bin = 0, lr = 0;
    if (i < N_NODES) {
        int deg = (i < N_USERS) ? rpu[i + 1] - rpu[i]
                                : rpi[i - N_USERS + 1] - rpi[i - N_USERS];
        bin = min(deg, 255);
        lr = atomicAdd(&lh[bin], 1);
    }
    __syncthreads();
    if (lh[tid]) lbase[tid] = atomicAdd(&gcur[tid * BPAD], lh[tid]);
    __syncthreads();
    if (i < N_NODES) perm[lbase[bin] + lr] = i;
}

// ---- prep: z0 = dinv*in_embs in bf16; zero phantom row in zP & zQ ----
__global__ __launch_bounds__(256) void prep0(
    const float* __restrict__ init, const float* __restrict__ dinv,
    unsigned short* __restrict__ zP, unsigned short* __restrict__ zQ)
{
    int i = blockIdx.x * 256 + threadIdx.x;      // uint2 (4 bf16) units
    const int TOT = N_NODES * 16;
    if (i < TOT) {
        int r = i >> 4;
        float dv = dinv[r];
        float4 x = reinterpret_cast<const float4*>(init)[i];
        unsigned lo0 = f2bf(x.x * dv), hi0 = f2bf(x.y * dv);
        unsigned lo1 = f2bf(x.z * dv), hi1 = f2bf(x.w * dv);
        uint2 o; o.x = lo0 | (hi0 << 16); o.y = lo1 | (hi1 << 16);
        reinterpret_cast<uint2*>(zP)[i] = o;
    } else if (i < TOT + 16) {
        uint2 zz; zz.x = 0; zz.y = 0;
        reinterpret_cast<uint2*>(zP)[i] = zz;
        reinterpret_cast<uint2*>(zQ)[i] = zz;
    }
}

// ---- fused SpMM + L2-normalize (+ z write | final combine) ----
// 8-lane group per row (degree-sorted), lane owns an 8-dim (16 B) slice.
#define ACC8(r) do { \
    a0 += bflo(r.x); a1 += bfhi(r.x); \
    a2 += bflo(r.y); a3 += bfhi(r.y); \
    a4 += bflo(r.z); a5 += bfhi(r.z); \
    a6 += bflo(r.w); a7 += bfhi(r.w); } while (0)

template<int LAST>
__global__ __launch_bounds__(256) void spmm8(
    const unsigned short* __restrict__ z,
    const int* __restrict__ perm,
    const int* __restrict__ rpu,
    const int* __restrict__ rpi,
    const int* __restrict__ cols_u,
    const int* __restrict__ csr_col_i,
    const float* __restrict__ dinv,
    unsigned short* __restrict__ zout,
    const unsigned short* z1,
    const unsigned short* z2,
    const float* __restrict__ init,
    float* __restrict__ out)
{
    const int tid = threadIdx.x;
    const int lane = tid & 63;
    const int g  = lane >> 3;
    const int sl = lane & 7;
    const int wave = tid >> 6;
    const int slot = blockIdx.x * 32 + wave * 8 + g;
    if (slot >= N_NODES) return;
    const int row = perm[slot];
    const int gb = g << 3;
    const int ZR = N_NODES;                     // phantom zero row

    int beg, end;
    const int* clist;
    if (row < N_USERS) {
        beg = rpu[row]; end = rpu[row + 1]; clist = cols_u;
    } else {
        int v = row - N_USERS;
        beg = rpi[v]; end = rpi[v + 1]; clist = csr_col_i;
    }

    float a0=0.f,a1=0.f,a2=0.f,a3=0.f,a4=0.f,a5=0.f,a6=0.f,a7=0.f;
    const unsigned short* zs = z + (size_t)sl * 8;

    int j = beg;
    for (; j + 16 <= end; j += 16) {
        int cA = clist[j + sl];
        int cB = clist[j + 8 + sl];
        int A0=__shfl(cA,gb+0), A1=__shfl(cA,gb+1), A2=__shfl(cA,gb+2), A3=__shfl(cA,gb+3);
        int A4=__shfl(cA,gb+4), A5=__shfl(cA,gb+5), A6=__shfl(cA,gb+6), A7=__shfl(cA,gb+7);
        uint4 rA0 = *reinterpret_cast<const uint4*>(zs + (size_t)A0 * D);
        uint4 rA1 = *reinterpret_cast<const uint4*>(zs + (size_t)A1 * D);
        uint4 rA2 = *reinterpret_cast<const uint4*>(zs + (size_t)A2 * D);
        uint4 rA3 = *reinterpret_cast<const uint4*>(zs + (size_t)A3 * D);
        int B0=__shfl(cB,gb+0), B1=__shfl(cB,gb+1), B2=__shfl(cB,gb+2), B3=__shfl(cB,gb+3);
        int B4=__shfl(cB,gb+4), B5=__shfl(cB,gb+5), B6=__shfl(cB,gb+6), B7=__shfl(cB,gb+7);
        uint4 rA4 = *reinterpret_cast<const uint4*>(zs + (size_t)A4 * D);
        uint4 rA5 = *reinterpret_cast<const uint4*>(zs + (size_t)A5 * D);
        uint4 rA6 = *reinterpret_cast<const uint4*>(zs + (size_t)A6 * D);
        uint4 rA7 = *reinterpret_cast<const uint4*>(zs + (size_t)A7 * D);
        uint4 rB0 = *reinterpret_cast<const uint4*>(zs + (size_t)B0 * D);
        uint4 rB1 = *reinterpret_cast<const uint4*>(zs + (size_t)B1 * D);
        uint4 rB2 = *reinterpret_cast<const uint4*>(zs + (size_t)B2 * D);
        uint4 rB3 = *reinterpret_cast<const uint4*>(zs + (size_t)B3 * D);
        uint4 rB4 = *reinterpret_cast<const uint4*>(zs + (size_t)B4 * D);
        uint4 rB5 = *reinterpret_cast<const uint4*>(zs + (size_t)B5 * D);
        uint4 rB6 = *reinterpret_cast<const uint4*>(zs + (size_t)B6 * D);
        uint4 rB7 = *reinterpret_cast<const uint4*>(zs + (size_t)B7 * D);
        ACC8(rA0); ACC8(rA1); ACC8(rA2); ACC8(rA3);
        ACC8(rA4); ACC8(rA5); ACC8(rA6); ACC8(rA7);
        ACC8(rB0); ACC8(rB1); ACC8(rB2); ACC8(rB3);
        ACC8(rB4); ACC8(rB5); ACC8(rB6); ACC8(rB7);
    }
    if (j + 8 <= end) {
        int c = clist[j + sl];
        int C0=__shfl(c,gb+0), C1=__shfl(c,gb+1), C2=__shfl(c,gb+2), C3=__shfl(c,gb+3);
        int C4=__shfl(c,gb+4), C5=__shfl(c,gb+5), C6=__shfl(c,gb+6), C7=__shfl(c,gb+7);
        uint4 r0 = *reinterpret_cast<const uint4*>(zs + (size_t)C0 * D);
        uint4 r1 = *reinterpret_cast<const uint4*>(zs + (size_t)C1 * D);
        uint4 r2 = *reinterpret_cast<const uint4*>(zs + (size_t)C2 * D);
        uint4 r3 = *reinterpret_cast<const uint4*>(zs + (size_t)C3 * D);
        uint4 r4 = *reinterpret_cast<const uint4*>(zs + (size_t)C4 * D);
        uint4 r5 = *reinterpret_cast<const uint4*>(zs + (size_t)C5 * D);
        uint4 r6 = *reinterpret_cast<const uint4*>(zs + (size_t)C6 * D);
        uint4 r7 = *reinterpret_cast<const uint4*>(zs + (size_t)C7 * D);
        ACC8(r0); ACC8(r1); ACC8(r2); ACC8(r3);
        ACC8(r4); ACC8(r5); ACC8(r6); ACC8(r7);
        j += 8;
    }
    if (j < end) {                               // phantom-padded remainder
        int c = (j + sl < end) ? clist[j + sl] : ZR;
        int C0=__shfl(c,gb+0), C1=__shfl(c,gb+1), C2=__shfl(c,gb+2), C3=__shfl(c,gb+3);
        int C4=__shfl(c,gb+4), C5=__shfl(c,gb+5), C6=__shfl(c,gb+6), C7=__shfl(c,gb+7);
        uint4 r0 = *reinterpret_cast<const uint4*>(zs + (size_t)C0 * D);
        uint4 r1 = *reinterpret_cast<const uint4*>(zs + (size_t)C1 * D);
        uint4 r2 = *reinterpret_cast<const uint4*>(zs + (size_t)C2 * D);
        uint4 r3 = *reinterpret_cast<const uint4*>(zs + (size_t)C3 * D);
        uint4 r4 = *reinterpret_cast<const uint4*>(zs + (size_t)C4 * D);
        uint4 r5 = *reinterpret_cast<const uint4*>(zs + (size_t)C5 * D);
        uint4 r6 = *reinterpret_cast<const uint4*>(zs + (size_t)C6 * D);
        uint4 r7 = *reinterpret_cast<const uint4*>(zs + (size_t)C7 * D);
        ACC8(r0); ACC8(r1); ACC8(r2); ACC8(r3);
        ACC8(r4); ACC8(r5); ACC8(r6); ACC8(r7);
    }

    float ss = a0*a0 + a1*a1 + a2*a2 + a3*a3 + a4*a4 + a5*a5 + a6*a6 + a7*a7;
    ss += __shfl_xor(ss, 1);
    ss += __shfl_xor(ss, 2);
    ss += __shfl_xor(ss, 4);
    float rinv = 1.0f / fmaxf(sqrtf(ss), 1e-12f);

    size_t idx = (size_t)row * D + (size_t)sl * 8;
    if (!LAST) {
        float sc = rinv * dinv[row];
        uint4 zo;
        zo.x = f2bf(a0 * sc) | (f2bf(a1 * sc) << 16);
        zo.y = f2bf(a2 * sc) | (f2bf(a3 * sc) << 16);
        zo.z = f2bf(a4 * sc) | (f2bf(a5 * sc) << 16);
        zo.w = f2bf(a6 * sc) | (f2bf(a7 * sc) << 16);
        *reinterpret_cast<uint4*>(zout + idx) = zo;
    } else {
        float recip = 1.0f / dinv[row];          // = sqrt(deg + eps)
        float k1 = recip, k2 = 0.5f * recip, k3 = rinv * (1.0f / 3.0f);
        uint4v w1 = __builtin_nontemporal_load(reinterpret_cast<const uint4v*>(z1 + idx));
        uint4v w2 = __builtin_nontemporal_load(reinterpret_cast<const uint4v*>(z2 + idx));
        const float4v* ip = reinterpret_cast<const float4v*>(init + idx);
        float4v o0 = __builtin_nontemporal_load(ip);
        float4v o1 = __builtin_nontemporal_load(ip + 1);
        o0.x += bflo(w1.x) * k1 + bflo(w2.x) * k2 + a0 * k3;
        o0.y += bfhi(w1.x) * k1 + bfhi(w2.x) * k2 + a1 * k3;
        o0.z += bflo(w1.y) * k1 + bflo(w2.y) * k2 + a2 * k3;
        o0.w += bfhi(w1.y) * k1 + bfhi(w2.y) * k2 + a3 * k3;
        o1.x += bflo(w1.z) * k1 + bflo(w2.z) * k2 + a4 * k3;
        o1.y += bfhi(w1.z) * k1 + bfhi(w2.z) * k2 + a5 * k3;
        o1.z += bflo(w1.w) * k1 + bflo(w2.w) * k2 + a6 * k3;
        o1.w += bfhi(w1.w) * k1 + bfhi(w2.w) * k2 + a7 * k3;
        float4v* op = reinterpret_cast<float4v*>(out + idx);
        __builtin_nontemporal_store(o0, op);
        __builtin_nontemporal_store(o1, op + 1);
    }
}

extern "C" void kernel_launch(void* const* d_in, const int* in_sizes, int n_in,
                              void* d_out, int out_size, void* d_ws, size_t ws_size,
                              hipStream_t stream) {
    const float* in_embs = (const float*)d_in[0];
    const int*   rows    = (const int*)d_in[1];
    const int*   cols    = (const int*)d_in[2];
    float* out = (float*)d_out;

    const int E  = in_sizes[1];
    const int Eh = E / 2;
    const size_t z_bytes = (size_t)(N_NODES + 1) * D * sizeof(unsigned short);

    auto align256 = [](size_t x) { return (x + 255) & ~(size_t)255; };
    char* p = (char*)d_ws;
    unsigned short* zP = (unsigned short*)p; p += align256(z_bytes);
    unsigned short* zQ = (unsigned short*)p; p += align256(z_bytes);
    int*   csr_col_i = (int*)p;   p += align256((size_t)Eh * sizeof(int));
    int*   rpu       = (int*)p;   p += align256((size_t)(N_USERS + 1) * sizeof(int));
    int*   rpi       = (int*)p;   p += align256((size_t)(N_ITEMS + 1) * sizeof(int));
    float* dinv      = (float*)p; p += align256((size_t)N_NODES * sizeof(float));
    int*   bcur      = (int*)p;   p += align256(256 * sizeof(int));
    int*   ghist     = (int*)p;   p += align256(256 * BPAD * sizeof(int));
    int*   gcur      = (int*)p;   p += align256(256 * BPAD * sizeof(int));
    int*   perm      = (int*)p;   p += align256((size_t)N_NODES * sizeof(int));
    // staging aliases zP; consumed by item_csr before prep0 writes zP
    int*   staging   = (int*)zP;

    // --- CSR build + degree sort ---
    hipMemsetAsync(ghist, 0, 256 * BPAD * sizeof(int), stream);
    edge_bounds<<<(Eh + 255) / 256, 256, 0, stream>>>(rows, rpu, bcur, Eh);
    user_dinv<<<(N_USERS + 255) / 256, 256, 0, stream>>>(rpu, dinv, ghist);
    bucket_scatter<<<(Eh + EPB - 1) / EPB, 256, 0, stream>>>(rows, cols, bcur, staging, Eh);
    item_csr<<<NBK, 256, 0, stream>>>(bcur, staging, rpi, dinv, csr_col_i, ghist);
    deg_scan<<<1, 256, 0, stream>>>(ghist, gcur);
    deg_scatter<<<(N_NODES + 255) / 256, 256, 0, stream>>>(rpu, rpi, gcur, perm);
    prep0<<<(N_NODES * 16 + 16 + 255) / 256, 256, 0, stream>>>(in_embs, dinv, zP, zQ);

    // --- 3 propagation layers ---
    const int grid = (N_NODES + 31) / 32;
    spmm8<0><<<grid, 256, 0, stream>>>(zP, perm, rpu, rpi, cols, csr_col_i, dinv,
                                       zQ, nullptr, nullptr, nullptr, nullptr);
    spmm8<0><<<grid, 256, 0, stream>>>(zQ, perm, rpu, rpi, cols, csr_col_i, dinv,
                                       zP, nullptr, nullptr, nullptr, nullptr);
    spmm8<1><<<grid, 256, 0, stream>>>(zP, perm, rpu, rpi, cols, csr_col_i, dinv,
                                       nullptr, zQ, zP, in_embs, out);
}

// Round 12
// 221.467 us; speedup vs baseline: 2.8823x; 1.1779x over previous
//
#include <hip/hip_runtime.h>
#include <hip/hip_bf16.h>

// LightGCN on MI355X — round 12: best-of configuration.
// spmm8 = R7 exact (8-lane groups, 8-gather loop, no permutation — the
// fastest of 4 measured spmm structures at ~61 µs/layer, bound by the
// L2-miss path for random 128 B row gathers).
// Build = R11's cheap path (boundary-fill rpu, LDS bucket sort for item CSR),
// minus all degree-sort machinery (falsified in R11).

constexpr int N_USERS = 100000;
constexpr int N_ITEMS = 50000;
constexpr int N_NODES = N_USERS + N_ITEMS;
constexpr int D = 64;
constexpr int NBK  = 196;
constexpr int SLOT = 12288;
constexpr int EPB  = 16384;

typedef unsigned int uint4v  __attribute__((ext_vector_type(4)));
typedef float        float4v __attribute__((ext_vector_type(4)));

__device__ inline unsigned f2bf(float f) {
    unsigned u = __float_as_uint(f);
    u += 0x7FFFu + ((u >> 16) & 1u);   // RNE
    return u >> 16;
}
__device__ inline float bflo(unsigned u) { return __uint_as_float(u << 16); }
__device__ inline float bfhi(unsigned u) { return __uint_as_float(u & 0xFFFF0000u); }

// ---- rpu via boundary fill over sorted rows[0:Eh]; also init bcur ----
__global__ __launch_bounds__(256) void edge_bounds(
    const int* __restrict__ rows, int* __restrict__ rpu,
    int* __restrict__ bcur, int Eh)
{
    if (blockIdx.x == 0 && threadIdx.x < NBK) bcur[threadIdx.x] = threadIdx.x * SLOT;
    int j = blockIdx.x * 256 + threadIdx.x;
    if (j >= Eh) return;
    int r = rows[j];
    int rprev = (j == 0) ? -1 : rows[j - 1];
    for (int k = rprev + 1; k <= r; ++k) rpu[k] = j;
    if (j == Eh - 1)
        for (int k = r + 1; k <= N_USERS; ++k) rpu[k] = Eh;
}

// ---- user dinv ----
__global__ __launch_bounds__(256) void user_dinv(
    const int* __restrict__ rpu, float* __restrict__ dinv)
{
    int i = blockIdx.x * 256 + threadIdx.x;
    if (i < N_USERS)
        dinv[i] = rsqrtf((float)(rpu[i + 1] - rpu[i]) + 1e-7f);
}

// ---- pass 1: bucket scatter of (u, vlocal) from the first edge half ----
__global__ __launch_bounds__(256) void bucket_scatter(
    const int* __restrict__ rows, const int* __restrict__ cols,
    int* __restrict__ bcur, int* __restrict__ staging, int Eh)
{
    __shared__ int hist[256];
    const int tid = threadIdx.x;
    const int base = blockIdx.x * EPB;
    const int nEdge = min(EPB, Eh - base);
    if (nEdge <= 0) return;

    hist[tid] = 0;
    __syncthreads();

    for (int s = 0; s < 16; ++s) {
        int o = s * 1024 + tid * 4;
        if (o + 3 < nEdge) {
            int4 c4 = *reinterpret_cast<const int4*>(cols + base + o);
            atomicAdd(&hist[(c4.x - N_USERS) >> 8], 1);
            atomicAdd(&hist[(c4.y - N_USERS) >> 8], 1);
            atomicAdd(&hist[(c4.z - N_USERS) >> 8], 1);
            atomicAdd(&hist[(c4.w - N_USERS) >> 8], 1);
        } else if (o < nEdge) {
            for (int k = o; k < nEdge; ++k)
                atomicAdd(&hist[(cols[base + k] - N_USERS) >> 8], 1);
        }
    }
    __syncthreads();

    if (tid < NBK) {
        int h = hist[tid];
        hist[tid] = (h > 0) ? atomicAdd(&bcur[tid], h) : 0;
    }
    __syncthreads();

    for (int s = 0; s < 16; ++s) {
        int o = s * 1024 + tid * 4;
        if (o + 3 < nEdge) {
            int4 c4 = *reinterpret_cast<const int4*>(cols + base + o);
            int4 u4 = *reinterpret_cast<const int4*>(rows + base + o);
            int v, p;
            v = c4.x - N_USERS; p = atomicAdd(&hist[v >> 8], 1);
            staging[p] = ((v & 255) << 24) | u4.x;
            v = c4.y - N_USERS; p = atomicAdd(&hist[v >> 8], 1);
            staging[p] = ((v & 255) << 24) | u4.y;
            v = c4.z - N_USERS; p = atomicAdd(&hist[v >> 8], 1);
            staging[p] = ((v & 255) << 24) | u4.z;
            v = c4.w - N_USERS; p = atomicAdd(&hist[v >> 8], 1);
            staging[p] = ((v & 255) << 24) | u4.w;
        } else if (o < nEdge) {
            for (int k = o; k < nEdge; ++k) {
                int v = cols[base + k] - N_USERS;
                int u = rows[base + k];
                int p = atomicAdd(&hist[v >> 8], 1);
                staging[p] = ((v & 255) << 24) | u;
            }
        }
    }
}

// ---- pass 2: per-bucket sort -> item CSR + rpi + item dinv (scan fused) ----
__global__ __launch_bounds__(256) void item_csr(
    const int* __restrict__ bcur, const int* __restrict__ staging,
    int* __restrict__ rpi, float* __restrict__ dinv, int* __restrict__ csr)
{
    __shared__ int hist[256];
    __shared__ int cur[256];
    __shared__ int wsum[4];
    __shared__ int s_cbase;
    const int b = blockIdx.x;
    const int tid = threadIdx.x, lane = tid & 63, w = tid >> 6;

    int tot = (tid < NBK) ? (bcur[tid] - tid * SLOT) : 0;
    int incl = tot;
    #pragma unroll
    for (int off = 1; off < 64; off <<= 1) {
        int s = __shfl_up(incl, off);
        if (lane >= off) incl += s;
    }
    if (lane == 63) wsum[w] = incl;
    __syncthreads();
    int woff = 0;
    #pragma unroll
    for (int k = 0; k < 4; ++k) woff += (k < w) ? wsum[k] : 0;
    int excl = woff + incl - tot;
    if (tid == b) s_cbase = excl;
    if (b == 0 && tid == NBK - 1) rpi[N_ITEMS] = excl + tot;
    __syncthreads();

    const int sbase = b * SLOT;
    const int n = bcur[b] - sbase;
    const int cbase = s_cbase;

    hist[tid] = 0;
    __syncthreads();
    for (int i = tid; i < n; i += 256)
        atomicAdd(&hist[((unsigned)staging[sbase + i]) >> 24], 1);
    __syncthreads();

    int h = hist[tid];
    int incl2 = h;
    #pragma unroll
    for (int off = 1; off < 64; off <<= 1) {
        int s = __shfl_up(incl2, off);
        if (lane >= off) incl2 += s;
    }
    if (lane == 63) wsum[w] = incl2;
    __syncthreads();
    int woff2 = 0;
    #pragma unroll
    for (int k = 0; k < 4; ++k) woff2 += (k < w) ? wsum[k] : 0;
    int excl2 = woff2 + incl2 - h;

    int gitem = b * 256 + tid;
    if (gitem < N_ITEMS) {
        rpi[gitem] = cbase + excl2;
        dinv[N_USERS + gitem] = rsqrtf((float)h + 1e-7f);
    }
    cur[tid] = cbase + excl2;
    __syncthreads();

    for (int i = tid; i < n; i += 256) {
        int e = staging[sbase + i];
        int p = atomicAdd(&cur[((unsigned)e) >> 24], 1);
        csr[p] = e & 0xFFFFFF;
    }
}

// ---- prep: z0[r] = dinv[r] * in_embs[r] in bf16 ----
__global__ __launch_bounds__(256) void prep0(
    const float* __restrict__ init, const float* __restrict__ dinv,
    unsigned short* __restrict__ z)
{
    int i = blockIdx.x * 256 + threadIdx.x;     // uint2 (4 bf16) per thread
    if (i >= N_NODES * 16) return;
    int r = i >> 4;
    float dv = dinv[r];
    float4 x = reinterpret_cast<const float4*>(init)[i];
    unsigned lo0 = f2bf(x.x * dv), hi0 = f2bf(x.y * dv);
    unsigned lo1 = f2bf(x.z * dv), hi1 = f2bf(x.w * dv);
    uint2 o; o.x = lo0 | (hi0 << 16); o.y = lo1 | (hi1 << 16);
    reinterpret_cast<uint2*>(z)[i] = o;
}

// ---- fused SpMM + L2-normalize (+ z write | final combine) — R7 exact ----
// 256 threads = 4 waves = 32 rows; 8-lane groups; uint4 (8 dims) per lane.
#define ACC8(r) do { \
    a0 += bflo(r.x); a1 += bfhi(r.x); \
    a2 += bflo(r.y); a3 += bfhi(r.y); \
    a4 += bflo(r.z); a5 += bfhi(r.z); \
    a6 += bflo(r.w); a7 += bfhi(r.w); } while (0)

template<int LAST>
__global__ __launch_bounds__(256) void spmm8(
    const unsigned short* __restrict__ z,
    const int* __restrict__ rpu,
    const int* __restrict__ rpi,
    const int* __restrict__ cols_u,
    const int* __restrict__ csr_col_i,
    const float* __restrict__ dinv,
    unsigned short* __restrict__ zout,
    const unsigned short* z1,
    const unsigned short* z2,
    const float* __restrict__ init,
    float* __restrict__ out)
{
    const int tid = threadIdx.x;
    const int lane = tid & 63;
    const int g  = lane >> 3;
    const int sl = lane & 7;
    const int wave = tid >> 6;
    const int row = blockIdx.x * 32 + wave * 8 + g;
    if (row >= N_NODES) return;
    const int gb = g << 3;

    int beg, end;
    const int* clist;
    if (row < N_USERS) {
        beg = rpu[row]; end = rpu[row + 1]; clist = cols_u;
    } else {
        int v = row - N_USERS;
        beg = rpi[v]; end = rpi[v + 1]; clist = csr_col_i;
    }

    float a0=0.f,a1=0.f,a2=0.f,a3=0.f,a4=0.f,a5=0.f,a6=0.f,a7=0.f;
    const unsigned short* zs = z + (size_t)sl * 8;

    int j = beg;
    for (; j + 8 <= end; j += 8) {
        int c_l = clist[j + sl];
        int c0 = __shfl(c_l, gb + 0);
        int c1 = __shfl(c_l, gb + 1);
        int c2 = __shfl(c_l, gb + 2);
        int c3 = __shfl(c_l, gb + 3);
        int c4 = __shfl(c_l, gb + 4);
        int c5 = __shfl(c_l, gb + 5);
        int c6 = __shfl(c_l, gb + 6);
        int c7 = __shfl(c_l, gb + 7);
        uint4 r0 = *reinterpret_cast<const uint4*>(zs + (size_t)c0 * D);
        uint4 r1 = *reinterpret_cast<const uint4*>(zs + (size_t)c1 * D);
        uint4 r2 = *reinterpret_cast<const uint4*>(zs + (size_t)c2 * D);
        uint4 r3 = *reinterpret_cast<const uint4*>(zs + (size_t)c3 * D);
        uint4 r4 = *reinterpret_cast<const uint4*>(zs + (size_t)c4 * D);
        uint4 r5 = *reinterpret_cast<const uint4*>(zs + (size_t)c5 * D);
        uint4 r6 = *reinterpret_cast<const uint4*>(zs + (size_t)c6 * D);
        uint4 r7 = *reinterpret_cast<const uint4*>(zs + (size_t)c7 * D);
        ACC8(r0); ACC8(r1); ACC8(r2); ACC8(r3);
        ACC8(r4); ACC8(r5); ACC8(r6); ACC8(r7);
    }
    int rem = end - j;
    if (rem > 0) {
        int c_l = (j + sl < end) ? clist[j + sl] : 0;
        for (int k = 0; k < rem; ++k) {
            int c = __shfl(c_l, gb + k);
            uint4 r = *reinterpret_cast<const uint4*>(zs + (size_t)c * D);
            ACC8(r);
        }
    }

    float ss = a0*a0 + a1*a1 + a2*a2 + a3*a3 + a4*a4 + a5*a5 + a6*a6 + a7*a7;
    ss += __shfl_xor(ss, 1);
    ss += __shfl_xor(ss, 2);
    ss += __shfl_xor(ss, 4);
    float rinv = 1.0f / fmaxf(sqrtf(ss), 1e-12f);

    size_t idx = (size_t)row * D + (size_t)sl * 8;
    if (!LAST) {
        float sc = rinv * dinv[row];
        uint4 zo;
        zo.x = f2bf(a0 * sc) | (f2bf(a1 * sc) << 16);
        zo.y = f2bf(a2 * sc) | (f2bf(a3 * sc) << 16);
        zo.z = f2bf(a4 * sc) | (f2bf(a5 * sc) << 16);
        zo.w = f2bf(a6 * sc) | (f2bf(a7 * sc) << 16);
        *reinterpret_cast<uint4*>(zout + idx) = zo;
    } else {
        float recip = 1.0f / dinv[row];          // = sqrt(deg + eps)
        float k1 = recip, k2 = 0.5f * recip, k3 = rinv * (1.0f / 3.0f);
        uint4v w1 = __builtin_nontemporal_load(reinterpret_cast<const uint4v*>(z1 + idx));
        uint4v w2 = __builtin_nontemporal_load(reinterpret_cast<const uint4v*>(z2 + idx));
        const float4v* ip = reinterpret_cast<const float4v*>(init + idx);
        float4v o0 = __builtin_nontemporal_load(ip);
        float4v o1 = __builtin_nontemporal_load(ip + 1);
        o0.x += bflo(w1.x) * k1 + bflo(w2.x) * k2 + a0 * k3;
        o0.y += bfhi(w1.x) * k1 + bfhi(w2.x) * k2 + a1 * k3;
        o0.z += bflo(w1.y) * k1 + bflo(w2.y) * k2 + a2 * k3;
        o0.w += bfhi(w1.y) * k1 + bfhi(w2.y) * k2 + a3 * k3;
        o1.x += bflo(w1.z) * k1 + bflo(w2.z) * k2 + a4 * k3;
        o1.y += bfhi(w1.z) * k1 + bfhi(w2.z) * k2 + a5 * k3;
        o1.z += bflo(w1.w) * k1 + bflo(w2.w) * k2 + a6 * k3;
        o1.w += bfhi(w1.w) * k1 + bfhi(w2.w) * k2 + a7 * k3;
        float4v* op = reinterpret_cast<float4v*>(out + idx);
        __builtin_nontemporal_store(o0, op);
        __builtin_nontemporal_store(o1, op + 1);
    }
}

extern "C" void kernel_launch(void* const* d_in, const int* in_sizes, int n_in,
                              void* d_out, int out_size, void* d_ws, size_t ws_size,
                              hipStream_t stream) {
    const float* in_embs = (const float*)d_in[0];
    const int*   rows    = (const int*)d_in[1];
    const int*   cols    = (const int*)d_in[2];
    float* out = (float*)d_out;

    const int E  = in_sizes[1];
    const int Eh = E / 2;
    const size_t z_bytes = (size_t)N_NODES * D * sizeof(unsigned short); // 19.2 MB

    auto align256 = [](size_t x) { return (x + 255) & ~(size_t)255; };
    char* p = (char*)d_ws;
    unsigned short* zP = (unsigned short*)p; p += align256(z_bytes);
    unsigned short* zQ = (unsigned short*)p; p += align256(z_bytes);
    int*   csr_col_i = (int*)p;   p += align256((size_t)Eh * sizeof(int));
    int*   rpu       = (int*)p;   p += align256((size_t)(N_USERS + 1) * sizeof(int));
    int*   rpi       = (int*)p;   p += align256((size_t)(N_ITEMS + 1) * sizeof(int));
    float* dinv      = (float*)p; p += align256((size_t)N_NODES * sizeof(float));
    int*   bcur      = (int*)p;   p += align256(256 * sizeof(int));
    // staging aliases zP (9.63 MB < 19.2 MB); consumed by item_csr before prep0
    int*   staging   = (int*)zP;

    // --- CSR build (5 dispatches) ---
    edge_bounds<<<(Eh + 255) / 256, 256, 0, stream>>>(rows, rpu, bcur, Eh);
    user_dinv<<<(N_USERS + 255) / 256, 256, 0, stream>>>(rpu, dinv);
    bucket_scatter<<<(Eh + EPB - 1) / EPB, 256, 0, stream>>>(rows, cols, bcur, staging, Eh);
    item_csr<<<NBK, 256, 0, stream>>>(bcur, staging, rpi, dinv, csr_col_i);
    prep0<<<(N_NODES * 16 + 255) / 256, 256, 0, stream>>>(in_embs, dinv, zP);

    // --- 3 propagation layers ---
    const int grid = (N_NODES + 31) / 32;
    spmm8<0><<<grid, 256, 0, stream>>>(zP, rpu, rpi, cols, csr_col_i, dinv,
                                       zQ, nullptr, nullptr, nullptr, nullptr);
    spmm8<0><<<grid, 256, 0, stream>>>(zQ, rpu, rpi, cols, csr_col_i, dinv,
                                       zP, nullptr, nullptr, nullptr, nullptr);
    spmm8<1><<<grid, 256, 0, stream>>>(zP, rpu, rpi, cols, csr_col_i, dinv,
                                       nullptr, zQ, zP, in_embs, out);
}